// Round 14
// baseline (295.447 us; speedup 1.0000x reference)
//
#include <hip/hip_runtime.h>
#include <math.h>

// Problem constants (fixed by setup_inputs)
constexpr int B_   = 2;
constexpr int C_   = 64;
constexpr int H_   = 128;
constexpr int W_   = 128;
constexpr int HW_  = H_ * W_;
constexpr int DG_  = 16;   // deformable groups
constexpr int KK_  = 9;    // 3x3 taps
constexpr int CG_  = 4;    // channels per group = C/DG
constexpr int OFFC_ = 3 * KK_ * DG_;  // 432
constexpr int R_   = C_ * KK_;        // 576 reduction length
constexpr int WP_  = 130;             // padded width/height
constexpr int HWP_ = WP_ * WP_;       // 16900 padded pixels

typedef _Float16 half8 __attribute__((ext_vector_type(8)));  // 8 f16 = 4 VGPR
typedef _Float16 half4 __attribute__((ext_vector_type(4)));  // 8-byte load/store
typedef float floatx4 __attribute__((ext_vector_type(4)));   // MFMA acc

// ---------------------------------------------------------------------------
// Generic MFMA A-operand prep: wA[(t*CH+h)*OC + oc][j] = f16(w[oc][(h*32+j)*9+t])
// ---------------------------------------------------------------------------
template <int OC, int CIN>
__global__ __launch_bounds__(256) void prep_wA_k(
    const float* __restrict__ w, _Float16* __restrict__ wA)
{
    constexpr int CH = CIN / 32;
    const int j = blockIdx.x * 256 + threadIdx.x;   // slab*OC*32 + oc*32 + jj
    if (j >= 9 * CH * OC * 32) return;
    const int slab = j / (OC * 32);
    const int rem  = j - slab * (OC * 32);
    const int oc   = rem >> 5;
    const int jj   = rem & 31;
    const int t    = slab / CH;
    const int h    = slab - t * CH;
    const int ic   = h * 32 + jj;
    wA[j] = (_Float16)w[(size_t)oc * (CIN * 9) + ic * 9 + t];
}

// ---------------------------------------------------------------------------
// Einsum A-operand prep: r = k*64 + gc (gc = g*4+c).  18 slabs of 32.
// ---------------------------------------------------------------------------
__global__ __launch_bounds__(256) void prep_wkA_k(
    const float* __restrict__ wk, _Float16* __restrict__ wkA)
{
    const int j = blockIdx.x * 256 + threadIdx.x;   // s*2048 + oc*32 + jj
    if (j >= 18 * 64 * 32) return;
    const int s   = j >> 11;
    const int rem = j & 2047;
    const int oc  = rem >> 5;
    const int jj  = rem & 31;
    const int k   = s >> 1;
    const int gc  = (s & 1) * 32 + jj;
    wkA[j] = (_Float16)wk[(size_t)oc * R_ + gc * 9 + k];
}

// ---------------------------------------------------------------------------
// NCHW fp32 -> PADDED slab-split f16: out[(c/32)*B + b][y+1][x+1][32].
// Borders pre-zeroed by hipMemsetAsync -> conv loads need no predication.
// ---------------------------------------------------------------------------
template <int CC>
__global__ __launch_bounds__(256) void nchw2slabpad_f16_k(
    const float* __restrict__ in, _Float16* __restrict__ outh)
{
    const int pix = blockIdx.x * 256 + threadIdx.x;
    const int b   = blockIdx.y;
    const int yp  = pix >> 7;
    const int xp  = pix & (W_ - 1);
    const float* ib = in + (size_t)b * CC * HW_ + pix;
#pragma unroll
    for (int c0 = 0; c0 < CC; c0 += 8) {
        half8 v;
#pragma unroll
        for (int j = 0; j < 8; ++j)
            v[j] = (_Float16)ib[(size_t)(c0 + j) * HW_];
        const int slab = c0 >> 5;
        *(half8*)&outh[((size_t)(slab * B_ + b) * HWP_
                        + (size_t)(yp + 1) * WP_ + (xp + 1)) * 32 + (c0 & 31)] = v;
    }
}

// ---------------------------------------------------------------------------
// NCHW fp32 -> plain NHWC f16 (for gather's x: half4 at g*4 within 64-rec).
// ---------------------------------------------------------------------------
template <int CC>
__global__ __launch_bounds__(256) void nchw2nhwc_f16_k(
    const float* __restrict__ in, _Float16* __restrict__ outh)
{
    const int pix = blockIdx.x * 256 + threadIdx.x;
    const int b   = blockIdx.y;
    const float* ib = in + (size_t)b * CC * HW_ + pix;
    _Float16* ob = outh + ((size_t)b * HW_ + pix) * CC;
#pragma unroll
    for (int c0 = 0; c0 < CC; c0 += 8) {
        half8 v;
#pragma unroll
        for (int j = 0; j < 8; ++j)
            v[j] = (_Float16)ib[(size_t)(c0 + j) * HW_];
        *(half8*)&ob[c0] = v;
    }
}

// ---------------------------------------------------------------------------
// Conv1/conv2 (CIN -> 64) via f16 MFMA, padded input -> UNCONDITIONAL loads,
// fully unrolled tap loop (compiler batches loads under vmcnt). Output is
// padded slab-split f16 (interior only; borders stay memset-zero).
// ---------------------------------------------------------------------------
template <int CIN>
__global__ __launch_bounds__(256) void conv12_mfma_k(
    const _Float16* __restrict__ inp, const _Float16* __restrict__ wA,
    const float* __restrict__ bias, _Float16* __restrict__ outp)
{
    constexpr int CH = CIN / 32;
    const int tid  = threadIdx.x;
    const int lane = tid & 63;
    const int wv   = tid >> 6;
    const int l15  = lane & 15;
    const int quad = lane >> 4;

    const int zx   = blockIdx.x;          // (b*H + y)*2 + half64
    const int row  = zx >> 1;
    const int b    = row >> 7;
    const int y    = row & 127;
    const int px0  = (zx & 1) * 64 + wv * 16;
    const int oct  = blockIdx.y;          // oc tile (16 chans)

    floatx4 acc = (floatx4){0.f, 0.f, 0.f, 0.f};

#pragma unroll
    for (int t = 0; t < 9; ++t) {
        const int dy = t / 3, dx = t % 3;
        const _Float16* ap = wA + ((size_t)(t * CH) * 64 + oct * 16 + l15) * 32 + quad * 8;
#pragma unroll
        for (int h = 0; h < CH; ++h) {
            const half8 bfr = *(const half8*)&inp[
                ((size_t)(h * B_ + b) * HWP_ + (size_t)(y + dy) * WP_
                 + (px0 + l15 + dx)) * 32 + quad * 8];
            const half8 afr = *(const half8*)&ap[(size_t)h * 64 * 32];
            acc = __builtin_amdgcn_mfma_f32_16x16x32_f16(afr, bfr, acc, 0, 0, 0);
        }
    }

    // epilogue: leaky ReLU, padded slab-split f16 store (8 B/lane)
    const int oc4 = oct * 16 + quad * 4;        // first of 4 output chans
    half4 v4;
#pragma unroll
    for (int reg = 0; reg < 4; ++reg) {
        float r = acc[reg] + bias[oc4 + reg];
        r = (r >= 0.f) ? r : 0.1f * r;
        v4[reg] = (_Float16)r;
    }
    *(half4*)&outp[((size_t)((oc4 >> 5) * B_ + b) * HWP_
                    + (size_t)(y + 1) * WP_ + (px0 + l15 + 1)) * 32 + (oc4 & 31)] = v4;
}

// ---------------------------------------------------------------------------
// Conv3 via f16 MFMA implicit GEMM, padded input -> unconditional B loads,
// fully unrolled K loop, LDS-staged f16 omap epilogue.
// Tile: wave = 32 px (nf=2) x 48 oc (mf=3); grid (B*H, 9) = 2304 blocks.
// LDS: 48 x 132 floats = 25.3 KB, write-once -> single barrier -> read-only.
// ---------------------------------------------------------------------------
__global__ __launch_bounds__(256) void conv3_mfma_k(
    const _Float16* __restrict__ h2p, const _Float16* __restrict__ w3A,
    const float* __restrict__ bias, const float* __restrict__ flow,
    _Float16* __restrict__ omh)
{
    __shared__ __align__(16) float Lds[48 * 132];

    const int tid  = threadIdx.x;
    const int lane = tid & 63;
    const int wv   = tid >> 6;       // wave id 0..3
    const int l15  = lane & 15;
    const int quad = lane >> 4;

    const int row = blockIdx.x;      // b*128 + y
    const int b   = row >> 7;
    const int y   = row & 127;
    const int m0  = blockIdx.y * 48; // oc tile base
    const int px0 = wv * 32;

    floatx4 acc[3][2];
#pragma unroll
    for (int mf = 0; mf < 3; ++mf)
#pragma unroll
        for (int nf = 0; nf < 2; ++nf)
            acc[mf][nf] = (floatx4){0.f, 0.f, 0.f, 0.f};

#pragma unroll
    for (int t = 0; t < 9; ++t) {
        const int dy = t / 3, dx = t % 3;
#pragma unroll
        for (int h = 0; h < 2; ++h) {        // two 32-ic slabs of K
            half8 bfr[2];
#pragma unroll
            for (int nf = 0; nf < 2; ++nf)
                bfr[nf] = *(const half8*)&h2p[
                    ((size_t)(h * B_ + b) * HWP_ + (size_t)(y + dy) * WP_
                     + (px0 + nf * 16 + l15 + dx)) * 32 + quad * 8];
            const _Float16* wbase = w3A + ((size_t)(t * 2 + h) * OFFC_ + m0) * 32;
#pragma unroll
            for (int mf = 0; mf < 3; ++mf) {
                const half8 afr = *(const half8*)&wbase[(mf * 16 + l15) * 32 + quad * 8];
#pragma unroll
                for (int nf = 0; nf < 2; ++nf)
                    acc[mf][nf] = __builtin_amdgcn_mfma_f32_16x16x32_f16(
                        afr, bfr[nf], acc[mf][nf], 0, 0, 0);
            }
        }
    }

    // ---- transform + stage to LDS (each thread writes 24 unique slots) ----
#pragma unroll
    for (int mf = 0; mf < 3; ++mf) {
#pragma unroll
        for (int nf = 0; nf < 2; ++nf) {
#pragma unroll
            for (int reg = 0; reg < 4; ++reg) {
                const int ocl = mf * 16 + quad * 4 + reg;   // 0..47
                const int oc  = m0 + ocl;
                const int px  = px0 + nf * 16 + l15;
                float val = acc[mf][nf][reg] + bias[oc];
                if (oc < 2 * DG_ * KK_) {          // offset channels
                    const int slot = oc & 1;        // 0 = y, 1 = x
                    const float fl = flow[(size_t)(b * 2 + (1 - slot)) * HW_ + y * W_ + px];
                    const float e = __expf(2.f * val);      // tanh via exp
                    val = 10.f * (1.f - __fdividef(2.f, e + 1.f)) + fl;
                } else {                            // mask channels: sigmoid
                    val = __fdividef(1.f, 1.f + __expf(-val));
                }
                Lds[ocl * 132 + px] = val;
            }
        }
    }
    __syncthreads();   // single barrier; LDS read-only hereafter

    // ---- contiguous f16 copy-out: 48 plane-rows x 128 px ----
#pragma unroll
    for (int it = 0; it < 6; ++it) {
        const int j4 = it * 256 + tid;
        const int r  = j4 >> 5;
        const int c4 = j4 & 31;
        const int oc = m0 + r;
        int g, k, slot;
        if (oc < 2 * DG_ * KK_) {
            g = oc / 18;
            const int rem = oc - g * 18;
            k = rem >> 1;
            slot = rem & 1;
        } else {
            const int c = oc - 2 * DG_ * KK_;
            g = c / 9;
            k = c - g * 9;
            slot = 2;
        }
        half4 hv;
#pragma unroll
        for (int j = 0; j < 4; ++j)
            hv[j] = (_Float16)Lds[r * 132 + c4 * 4 + j];
        *(half4*)&omh[((size_t)((b * DG_ * KK_ + g * KK_ + k) * 3 + slot)) * HW_
                      + y * W_ + c4 * 4] = hv;
    }
}

// ---------------------------------------------------------------------------
// Phase A: bilinear gather -> f16 val in [b*HW+pix][r], r = k*64+g*4+c.
// ---------------------------------------------------------------------------
__global__ __launch_bounds__(256) void gather_k(
    const _Float16* __restrict__ xn, const _Float16* __restrict__ omh,
    _Float16* __restrict__ valh)
{
    const int tid = threadIdx.x;
    const int gi  = tid & 3;                  // g within quad group
    const int pl  = tid >> 2;                 // 0..63 pixel local
    const int pix = blockIdx.x * 64 + pl;
    const int zy  = blockIdx.y;               // b*36 + gq*9 + k
    const int b   = zy / 36;
    const int rem = zy - b * 36;
    const int gq  = rem / 9;
    const int k   = rem - gq * 9;
    const int g   = gq * 4 + gi;
    const int yp  = pix >> 7;
    const int xp  = pix & (W_ - 1);

    const size_t obase = ((size_t)((b * DG_ + g) * KK_ + k) * 3) * HW_ + pix;
    const float oy = (float)omh[obase];
    const float ox = (float)omh[obase + HW_];
    const float m  = (float)omh[obase + 2 * HW_];

    const float py = (float)(yp + (k / 3) - 1) + oy;
    const float px = (float)(xp + (k % 3) - 1) + ox;
    const float y0f = floorf(py);
    const float x0f = floorf(px);
    const float wy = py - y0f;
    const float wx = px - x0f;
    const int y0 = (int)y0f, x0 = (int)x0f;
    const int y1 = y0 + 1,  x1 = x0 + 1;
    const bool vy0 = ((unsigned)y0 < (unsigned)H_);
    const bool vy1 = ((unsigned)y1 < (unsigned)H_);
    const bool vx0 = ((unsigned)x0 < (unsigned)W_);
    const bool vx1 = ((unsigned)x1 < (unsigned)W_);
    const float w00 = vy0 && vx0 ? (1.f - wy) * (1.f - wx) : 0.f;
    const float w01 = vy0 && vx1 ? (1.f - wy) * wx         : 0.f;
    const float w10 = vy1 && vx0 ? wy * (1.f - wx)         : 0.f;
    const float w11 = vy1 && vx1 ? wy * wx                 : 0.f;
    const int i00 = (vy0 && vx0) ? y0 * W_ + x0 : 0;
    const int i01 = (vy0 && vx1) ? y0 * W_ + x1 : 0;
    const int i10 = (vy1 && vx0) ? y1 * W_ + x0 : 0;
    const int i11 = (vy1 && vx1) ? y1 * W_ + x1 : 0;

    const _Float16* xb = xn + (size_t)b * HW_ * C_ + g * CG_;
    const half4 p00 = *(const half4*)&xb[(size_t)i00 * C_];
    const half4 p01 = *(const half4*)&xb[(size_t)i01 * C_];
    const half4 p10 = *(const half4*)&xb[(size_t)i10 * C_];
    const half4 p11 = *(const half4*)&xb[(size_t)i11 * C_];

    half4 v4;
#pragma unroll
    for (int c = 0; c < CG_; ++c) {
        float v = w00 * (float)p00[c] + w01 * (float)p01[c]
                + w10 * (float)p10[c] + w11 * (float)p11[c];
        v4[c] = (_Float16)(v * m);
    }
    *(half4*)&valh[((size_t)(b * HW_ + pix)) * R_ + k * 64 + g * 4] = v4;
}

// ---------------------------------------------------------------------------
// Phase B: einsum via f16 MFMA. K split 3 ways; fp32 partials.
// ---------------------------------------------------------------------------
__global__ __launch_bounds__(256) void einsum_mfma_k(
    const _Float16* __restrict__ valh, const _Float16* __restrict__ wkA,
    float* __restrict__ part)
{
    const int tid  = threadIdx.x;
    const int lane = tid & 63;
    const int wv   = tid >> 6;
    const int l15  = lane & 15;
    const int quad = lane >> 4;

    const int pixg0 = blockIdx.x * 128 + wv * 32;   // global pixel (b*HW+pix)
    const int ks    = blockIdx.y;                   // K slice 0..2
    const int s0    = ks * 6;

    floatx4 acc[4][2];
#pragma unroll
    for (int mf = 0; mf < 4; ++mf)
#pragma unroll
        for (int nf = 0; nf < 2; ++nf)
            acc[mf][nf] = (floatx4){0.f, 0.f, 0.f, 0.f};

#pragma unroll
    for (int si = 0; si < 6; ++si) {
        const int s = s0 + si;
        half8 bfr[2];
#pragma unroll
        for (int nf = 0; nf < 2; ++nf)
            bfr[nf] = *(const half8*)&valh[
                (size_t)(pixg0 + nf * 16 + l15) * R_ + s * 32 + quad * 8];
        const _Float16* ap = wkA + (size_t)s * 64 * 32;
#pragma unroll
        for (int mf = 0; mf < 4; ++mf) {
            const half8 afr = *(const half8*)&ap[(mf * 16 + l15) * 32 + quad * 8];
#pragma unroll
            for (int nf = 0; nf < 2; ++nf)
                acc[mf][nf] = __builtin_amdgcn_mfma_f32_16x16x32_f16(
                    afr, bfr[nf], acc[mf][nf], 0, 0, 0);
        }
    }

#pragma unroll
    for (int mf = 0; mf < 4; ++mf) {
#pragma unroll
        for (int nf = 0; nf < 2; ++nf) {
#pragma unroll
            for (int reg = 0; reg < 4; ++reg) {
                const int pixg = pixg0 + nf * 16 + l15;
                const int b    = pixg >> 14;
                const int pix  = pixg & (HW_ - 1);
                const int oc   = mf * 16 + quad * 4 + reg;
                part[(size_t)ks * (B_ * C_ * HW_) +
                     ((size_t)(b * C_ + oc)) * HW_ + pix] = acc[mf][nf][reg];
            }
        }
    }
}

// ---------------------------------------------------------------------------
// Combine the 3 K-slice partials into d_out (float4 vectorized).
// ---------------------------------------------------------------------------
__global__ __launch_bounds__(256) void combine3_k(
    const float4* __restrict__ part, float4* __restrict__ out)
{
    constexpr int N4 = B_ * C_ * HW_ / 4;   // 524288
    const int i = blockIdx.x * 256 + threadIdx.x;
    if (i >= N4) return;
    float4 a = part[i];
    const float4 b = part[i + N4];
    const float4 c = part[i + 2 * N4];
    a.x += b.x + c.x;
    a.y += b.y + c.y;
    a.z += b.z + c.z;
    a.w += b.w + c.w;
    out[i] = a;
}

// ---------------------------------------------------------------------------
extern "C" void kernel_launch(void* const* d_in, const int* in_sizes, int n_in,
                              void* d_out, int out_size, void* d_ws, size_t ws_size,
                              hipStream_t stream)
{
    const float* x    = (const float*)d_in[0];
    const float* ef   = (const float*)d_in[1];
    const float* flow = (const float*)d_in[2];
    const float* w1   = (const float*)d_in[3];
    const float* b1   = (const float*)d_in[4];
    const float* w2   = (const float*)d_in[5];
    const float* b2   = (const float*)d_in[6];
    const float* w3   = (const float*)d_in[7];
    const float* b3   = (const float*)d_in[8];
    const float* wk   = (const float*)d_in[9];
    float* out = (float*)d_out;

    // Workspace (half slots):
    //   omh 14,155,776 | valh 18,874,368 | ef_p 4*B*HWP*32 = 4,326,400
    //   xn 2,097,152 | h1p 2*B*HWP*32 = 2,163,200 | h2p 2,163,200
    //   w1A 73,728 | w2A 36,864 | w3A 248,832 | wkA 36,864
    //   part 3*B*C*HW floats (optional, else alias omh)
    _Float16* omh  = (_Float16*)d_ws;
    _Float16* valh = omh + (size_t)B_ * OFFC_ * HW_;
    _Float16* ef_p = valh + (size_t)B_ * HW_ * R_;
    _Float16* xn   = ef_p + (size_t)4 * B_ * HWP_ * 32;
    _Float16* h1p  = xn + (size_t)B_ * HW_ * 64;
    _Float16* h2p  = h1p + (size_t)2 * B_ * HWP_ * 32;
    _Float16* w1A  = h2p + (size_t)2 * B_ * HWP_ * 32;
    _Float16* w2A  = w1A + 64 * 128 * 9;
    _Float16* w3A  = w2A + 64 * 64 * 9;
    _Float16* wkA  = w3A + OFFC_ * 64 * 9;
    float*    end  = (float*)(wkA + 18 * 64 * 32);
    const size_t need_sep =
        ((char*)end - (char*)d_ws) + (size_t)3 * B_ * C_ * HW_ * 4;
    float*    part = (ws_size >= need_sep) ? end : (float*)omh;  // constant per deployment

    // Zero the padded buffers (borders must be 0; interiors overwritten).
    hipMemsetAsync(ef_p, 0, (size_t)4 * B_ * HWP_ * 32 * 2, stream);
    hipMemsetAsync(h1p, 0, (size_t)2 * B_ * HWP_ * 32 * 2, stream);
    hipMemsetAsync(h2p, 0, (size_t)2 * B_ * HWP_ * 32 * 2, stream);

    prep_wA_k<64, 128><<<dim3((64 * 128 * 9 + 255) / 256), 256, 0, stream>>>(w1, w1A);
    prep_wA_k<64, 64><<<dim3((64 * 64 * 9 + 255) / 256), 256, 0, stream>>>(w2, w2A);
    prep_wA_k<OFFC_, 64><<<dim3((OFFC_ * 64 * 9 + 255) / 256), 256, 0, stream>>>(w3, w3A);
    prep_wkA_k<<<dim3((18 * 64 * 32 + 255) / 256), 256, 0, stream>>>(wk, wkA);
    nchw2slabpad_f16_k<128><<<dim3(HW_ / 256, B_), 256, 0, stream>>>(ef, ef_p);
    nchw2nhwc_f16_k<64><<<dim3(HW_ / 256, B_), 256, 0, stream>>>(x, xn);

    conv12_mfma_k<128><<<dim3(B_ * H_ * 2, 4), 256, 0, stream>>>(ef_p, w1A, b1, h1p);
    conv12_mfma_k<64><<<dim3(B_ * H_ * 2, 4), 256, 0, stream>>>(h1p, w2A, b2, h2p);
    conv3_mfma_k<<<dim3(B_ * H_, 9), 256, 0, stream>>>(h2p, w3A, b3, flow, omh);

    gather_k<<<dim3(HW_ / 64, B_ * 4 * KK_), 256, 0, stream>>>(xn, omh, valh);
    einsum_mfma_k<<<dim3(B_ * HW_ / 128, 3), 256, 0, stream>>>(valh, wkA, part);
    combine3_k<<<dim3((B_ * C_ * HW_ / 4 + 255) / 256), 256, 0, stream>>>((const float4*)part, (float4*)out);
}

// Round 15
// 291.329 us; speedup vs baseline: 1.0141x; 1.0141x over previous
//
#include <hip/hip_runtime.h>
#include <math.h>

// Problem constants (fixed by setup_inputs)
constexpr int B_   = 2;
constexpr int C_   = 64;
constexpr int H_   = 128;
constexpr int W_   = 128;
constexpr int HW_  = H_ * W_;
constexpr int DG_  = 16;   // deformable groups
constexpr int KK_  = 9;    // 3x3 taps
constexpr int CG_  = 4;    // channels per group = C/DG
constexpr int OFFC_ = 3 * KK_ * DG_;  // 432
constexpr int R_   = C_ * KK_;        // 576 reduction length
constexpr int WP_  = 130;             // padded width/height
constexpr int HWP_ = WP_ * WP_;       // 16900 padded pixels

typedef _Float16 half8 __attribute__((ext_vector_type(8)));  // 8 f16 = 4 VGPR
typedef _Float16 half4 __attribute__((ext_vector_type(4)));  // 8-byte load/store
typedef float floatx4 __attribute__((ext_vector_type(4)));   // MFMA acc

// ---------------------------------------------------------------------------
// Generic MFMA A-operand prep: wA[(t*CH+h)*OC + oc][j] = f16(w[oc][(h*32+j)*9+t])
// ---------------------------------------------------------------------------
template <int OC, int CIN>
__global__ __launch_bounds__(256) void prep_wA_k(
    const float* __restrict__ w, _Float16* __restrict__ wA)
{
    constexpr int CH = CIN / 32;
    const int j = blockIdx.x * 256 + threadIdx.x;   // slab*OC*32 + oc*32 + jj
    if (j >= 9 * CH * OC * 32) return;
    const int slab = j / (OC * 32);
    const int rem  = j - slab * (OC * 32);
    const int oc   = rem >> 5;
    const int jj   = rem & 31;
    const int t    = slab / CH;
    const int h    = slab - t * CH;
    const int ic   = h * 32 + jj;
    wA[j] = (_Float16)w[(size_t)oc * (CIN * 9) + ic * 9 + t];
}

// ---------------------------------------------------------------------------
// Einsum A-operand prep: r = k*64 + gc (gc = g*4+c).  18 slabs of 32.
// ---------------------------------------------------------------------------
__global__ __launch_bounds__(256) void prep_wkA_k(
    const float* __restrict__ wk, _Float16* __restrict__ wkA)
{
    const int j = blockIdx.x * 256 + threadIdx.x;   // s*2048 + oc*32 + jj
    if (j >= 18 * 64 * 32) return;
    const int s   = j >> 11;
    const int rem = j & 2047;
    const int oc  = rem >> 5;
    const int jj  = rem & 31;
    const int k   = s >> 1;
    const int gc  = (s & 1) * 32 + jj;
    wkA[j] = (_Float16)wk[(size_t)oc * R_ + gc * 9 + k];
}

// ---------------------------------------------------------------------------
// NCHW fp32 -> PADDED slab-split f16: out[(c/32)*B + b][y+1][x+1][32].
// Borders pre-zeroed by hipMemsetAsync -> conv loads need no predication.
// ---------------------------------------------------------------------------
template <int CC>
__global__ __launch_bounds__(256) void nchw2slabpad_f16_k(
    const float* __restrict__ in, _Float16* __restrict__ outh)
{
    const int pix = blockIdx.x * 256 + threadIdx.x;
    const int b   = blockIdx.y;
    const int yp  = pix >> 7;
    const int xp  = pix & (W_ - 1);
    const float* ib = in + (size_t)b * CC * HW_ + pix;
#pragma unroll
    for (int c0 = 0; c0 < CC; c0 += 8) {
        half8 v;
#pragma unroll
        for (int j = 0; j < 8; ++j)
            v[j] = (_Float16)ib[(size_t)(c0 + j) * HW_];
        const int slab = c0 >> 5;
        *(half8*)&outh[((size_t)(slab * B_ + b) * HWP_
                        + (size_t)(yp + 1) * WP_ + (xp + 1)) * 32 + (c0 & 31)] = v;
    }
}

// ---------------------------------------------------------------------------
// NCHW fp32 -> plain NHWC f16 (for gather's x: half4 at g*4 within 64-rec).
// ---------------------------------------------------------------------------
template <int CC>
__global__ __launch_bounds__(256) void nchw2nhwc_f16_k(
    const float* __restrict__ in, _Float16* __restrict__ outh)
{
    const int pix = blockIdx.x * 256 + threadIdx.x;
    const int b   = blockIdx.y;
    const float* ib = in + (size_t)b * CC * HW_ + pix;
    _Float16* ob = outh + ((size_t)b * HW_ + pix) * CC;
#pragma unroll
    for (int c0 = 0; c0 < CC; c0 += 8) {
        half8 v;
#pragma unroll
        for (int j = 0; j < 8; ++j)
            v[j] = (_Float16)ib[(size_t)(c0 + j) * HW_];
        *(half8*)&ob[c0] = v;
    }
}

// ---------------------------------------------------------------------------
// Conv1/conv2 (CIN -> 64) via f16 MFMA, padded input -> UNCONDITIONAL loads,
// fully unrolled tap loop. Output padded slab-split f16.
// ---------------------------------------------------------------------------
template <int CIN>
__global__ __launch_bounds__(256) void conv12_mfma_k(
    const _Float16* __restrict__ inp, const _Float16* __restrict__ wA,
    const float* __restrict__ bias, _Float16* __restrict__ outp)
{
    constexpr int CH = CIN / 32;
    const int tid  = threadIdx.x;
    const int lane = tid & 63;
    const int wv   = tid >> 6;
    const int l15  = lane & 15;
    const int quad = lane >> 4;

    const int zx   = blockIdx.x;          // (b*H + y)*2 + half64
    const int row  = zx >> 1;
    const int b    = row >> 7;
    const int y    = row & 127;
    const int px0  = (zx & 1) * 64 + wv * 16;
    const int oct  = blockIdx.y;          // oc tile (16 chans)

    floatx4 acc = (floatx4){0.f, 0.f, 0.f, 0.f};

#pragma unroll
    for (int t = 0; t < 9; ++t) {
        const int dy = t / 3, dx = t % 3;
        const _Float16* ap = wA + ((size_t)(t * CH) * 64 + oct * 16 + l15) * 32 + quad * 8;
#pragma unroll
        for (int h = 0; h < CH; ++h) {
            const half8 bfr = *(const half8*)&inp[
                ((size_t)(h * B_ + b) * HWP_ + (size_t)(y + dy) * WP_
                 + (px0 + l15 + dx)) * 32 + quad * 8];
            const half8 afr = *(const half8*)&ap[(size_t)h * 64 * 32];
            acc = __builtin_amdgcn_mfma_f32_16x16x32_f16(afr, bfr, acc, 0, 0, 0);
        }
    }

    // epilogue: leaky ReLU, padded slab-split f16 store (8 B/lane)
    const int oc4 = oct * 16 + quad * 4;        // first of 4 output chans
    half4 v4;
#pragma unroll
    for (int reg = 0; reg < 4; ++reg) {
        float r = acc[reg] + bias[oc4 + reg];
        r = (r >= 0.f) ? r : 0.1f * r;
        v4[reg] = (_Float16)r;
    }
    *(half4*)&outp[((size_t)((oc4 >> 5) * B_ + b) * HWP_
                    + (size_t)(y + 1) * WP_ + (px0 + l15 + 1)) * 32 + (oc4 & 31)] = v4;
}

// ---------------------------------------------------------------------------
// Conv3 via f16 MFMA implicit GEMM, padded input, unconditional B loads,
// fully unrolled K loop, LDS-staged f16 omap epilogue.
// ---------------------------------------------------------------------------
__global__ __launch_bounds__(256) void conv3_mfma_k(
    const _Float16* __restrict__ h2p, const _Float16* __restrict__ w3A,
    const float* __restrict__ bias, const float* __restrict__ flow,
    _Float16* __restrict__ omh)
{
    __shared__ __align__(16) float Lds[48 * 132];

    const int tid  = threadIdx.x;
    const int lane = tid & 63;
    const int wv   = tid >> 6;       // wave id 0..3
    const int l15  = lane & 15;
    const int quad = lane >> 4;

    const int row = blockIdx.x;      // b*128 + y
    const int b   = row >> 7;
    const int y   = row & 127;
    const int m0  = blockIdx.y * 48; // oc tile base
    const int px0 = wv * 32;

    floatx4 acc[3][2];
#pragma unroll
    for (int mf = 0; mf < 3; ++mf)
#pragma unroll
        for (int nf = 0; nf < 2; ++nf)
            acc[mf][nf] = (floatx4){0.f, 0.f, 0.f, 0.f};

#pragma unroll
    for (int t = 0; t < 9; ++t) {
        const int dy = t / 3, dx = t % 3;
#pragma unroll
        for (int h = 0; h < 2; ++h) {        // two 32-ic slabs of K
            half8 bfr[2];
#pragma unroll
            for (int nf = 0; nf < 2; ++nf)
                bfr[nf] = *(const half8*)&h2p[
                    ((size_t)(h * B_ + b) * HWP_ + (size_t)(y + dy) * WP_
                     + (px0 + nf * 16 + l15 + dx)) * 32 + quad * 8];
            const _Float16* wbase = w3A + ((size_t)(t * 2 + h) * OFFC_ + m0) * 32;
#pragma unroll
            for (int mf = 0; mf < 3; ++mf) {
                const half8 afr = *(const half8*)&wbase[(mf * 16 + l15) * 32 + quad * 8];
#pragma unroll
                for (int nf = 0; nf < 2; ++nf)
                    acc[mf][nf] = __builtin_amdgcn_mfma_f32_16x16x32_f16(
                        afr, bfr[nf], acc[mf][nf], 0, 0, 0);
            }
        }
    }

    // ---- transform + stage to LDS (each thread writes 24 unique slots) ----
#pragma unroll
    for (int mf = 0; mf < 3; ++mf) {
#pragma unroll
        for (int nf = 0; nf < 2; ++nf) {
#pragma unroll
            for (int reg = 0; reg < 4; ++reg) {
                const int ocl = mf * 16 + quad * 4 + reg;   // 0..47
                const int oc  = m0 + ocl;
                const int px  = px0 + nf * 16 + l15;
                float val = acc[mf][nf][reg] + bias[oc];
                if (oc < 2 * DG_ * KK_) {          // offset channels
                    const int slot = oc & 1;        // 0 = y, 1 = x
                    const float fl = flow[(size_t)(b * 2 + (1 - slot)) * HW_ + y * W_ + px];
                    const float e = __expf(2.f * val);      // tanh via exp
                    val = 10.f * (1.f - __fdividef(2.f, e + 1.f)) + fl;
                } else {                            // mask channels: sigmoid
                    val = __fdividef(1.f, 1.f + __expf(-val));
                }
                Lds[ocl * 132 + px] = val;
            }
        }
    }
    __syncthreads();   // single barrier; LDS read-only hereafter

    // ---- contiguous f16 copy-out: 48 plane-rows x 128 px ----
#pragma unroll
    for (int it = 0; it < 6; ++it) {
        const int j4 = it * 256 + tid;
        const int r  = j4 >> 5;
        const int c4 = j4 & 31;
        const int oc = m0 + r;
        int g, k, slot;
        if (oc < 2 * DG_ * KK_) {
            g = oc / 18;
            const int rem = oc - g * 18;
            k = rem >> 1;
            slot = rem & 1;
        } else {
            const int c = oc - 2 * DG_ * KK_;
            g = c / 9;
            k = c - g * 9;
            slot = 2;
        }
        half4 hv;
#pragma unroll
        for (int j = 0; j < 4; ++j)
            hv[j] = (_Float16)Lds[r * 132 + c4 * 4 + j];
        *(half4*)&omh[((size_t)((b * DG_ * KK_ + g * KK_ + k) * 3 + slot)) * HW_
                      + y * W_ + c4 * 4] = hv;
    }
}

// ---------------------------------------------------------------------------
// Phase A: bilinear gather -> SLAB-SPLIT f16 val: [(s*B+b)*HW+pix][32],
// s = k*2 + g/8. Lane map: tid&15 = g, tid>>4 = pixel-local (16 px/block).
// 16 lanes (one pixel's 16 g's) write 128 contiguous B -> full-granule
// HBM writes (was 16-B segments). Grid (HW/16, B*9) = 9216 blocks.
// ---------------------------------------------------------------------------
__global__ __launch_bounds__(256) void gather_k(
    const _Float16* __restrict__ xn, const _Float16* __restrict__ omh,
    _Float16* __restrict__ valh)
{
    const int tid = threadIdx.x;
    const int g   = tid & 15;
    const int pl  = tid >> 4;                 // 0..15 pixel local
    const int pix = blockIdx.x * 16 + pl;
    const int zy  = blockIdx.y;               // b*9 + k
    const int b   = zy / KK_;
    const int k   = zy - b * KK_;
    const int yp  = pix >> 7;
    const int xp  = pix & (W_ - 1);

    const size_t obase = ((size_t)((b * DG_ + g) * KK_ + k) * 3) * HW_ + pix;
    const float oy = (float)omh[obase];
    const float ox = (float)omh[obase + HW_];
    const float m  = (float)omh[obase + 2 * HW_];

    const float py = (float)(yp + (k / 3) - 1) + oy;
    const float px = (float)(xp + (k % 3) - 1) + ox;
    const float y0f = floorf(py);
    const float x0f = floorf(px);
    const float wy = py - y0f;
    const float wx = px - x0f;
    const int y0 = (int)y0f, x0 = (int)x0f;
    const int y1 = y0 + 1,  x1 = x0 + 1;
    const bool vy0 = ((unsigned)y0 < (unsigned)H_);
    const bool vy1 = ((unsigned)y1 < (unsigned)H_);
    const bool vx0 = ((unsigned)x0 < (unsigned)W_);
    const bool vx1 = ((unsigned)x1 < (unsigned)W_);
    const float w00 = vy0 && vx0 ? (1.f - wy) * (1.f - wx) : 0.f;
    const float w01 = vy0 && vx1 ? (1.f - wy) * wx         : 0.f;
    const float w10 = vy1 && vx0 ? wy * (1.f - wx)         : 0.f;
    const float w11 = vy1 && vx1 ? wy * wx                 : 0.f;
    const int i00 = (vy0 && vx0) ? y0 * W_ + x0 : 0;
    const int i01 = (vy0 && vx1) ? y0 * W_ + x1 : 0;
    const int i10 = (vy1 && vx0) ? y1 * W_ + x0 : 0;
    const int i11 = (vy1 && vx1) ? y1 * W_ + x1 : 0;

    const _Float16* xb = xn + (size_t)b * HW_ * C_ + g * CG_;
    const half4 p00 = *(const half4*)&xb[(size_t)i00 * C_];
    const half4 p01 = *(const half4*)&xb[(size_t)i01 * C_];
    const half4 p10 = *(const half4*)&xb[(size_t)i10 * C_];
    const half4 p11 = *(const half4*)&xb[(size_t)i11 * C_];

    half4 v4;
#pragma unroll
    for (int c = 0; c < CG_; ++c) {
        float v = w00 * (float)p00[c] + w01 * (float)p01[c]
                + w10 * (float)p10[c] + w11 * (float)p11[c];
        v4[c] = (_Float16)(v * m);
    }
    const int s = k * 2 + (g >> 3);
    *(half4*)&valh[((size_t)(s * B_ + b) * HW_ + pix) * 32 + (g & 7) * 4] = v4;
}

// ---------------------------------------------------------------------------
// Phase B: einsum via f16 MFMA, SINGLE PASS (no K-split, no partials).
// Slab-split valh -> B-fragment load = 16 consecutive 64-B records = 1 KB
// contiguous. Wave = 16 px (nf=1) x 64 oc (mf=4); block = 4 waves = 64 px;
// grid = B*HW/64 = 512 blocks. Output staged in LDS (write-once -> barrier
// -> read-only) and copied to d_out in 256-B coalesced segments.
// ---------------------------------------------------------------------------
__global__ __launch_bounds__(256) void einsum_mfma_k(
    const _Float16* __restrict__ valh, const _Float16* __restrict__ wkA,
    float* __restrict__ out)
{
    __shared__ __align__(16) float Lds[64 * 68];   // 64 oc x 64 px (pad 68)

    const int tid  = threadIdx.x;
    const int lane = tid & 63;
    const int wv   = tid >> 6;
    const int l15  = lane & 15;
    const int quad = lane >> 4;

    const int pixg0 = blockIdx.x * 64 + wv * 16;    // global pixel (b*HW+pix)
    const int b     = pixg0 >> 14;
    const int pix0  = pixg0 & (HW_ - 1);

    floatx4 acc[4];
#pragma unroll
    for (int mf = 0; mf < 4; ++mf)
        acc[mf] = (floatx4){0.f, 0.f, 0.f, 0.f};

#pragma unroll
    for (int s = 0; s < 18; ++s) {
        const half8 bfr = *(const half8*)&valh[
            ((size_t)(s * B_ + b) * HW_ + pix0 + l15) * 32 + quad * 8];
        const _Float16* ap = wkA + (size_t)s * 64 * 32;
#pragma unroll
        for (int mf = 0; mf < 4; ++mf) {
            const half8 afr = *(const half8*)&ap[(mf * 16 + l15) * 32 + quad * 8];
            acc[mf] = __builtin_amdgcn_mfma_f32_16x16x32_f16(afr, bfr, acc[mf], 0, 0, 0);
        }
    }

    // ---- stage 64 oc x 64 px tile to LDS ----
    const int pxl = wv * 16 + l15;                  // 0..63 block-local pixel
#pragma unroll
    for (int mf = 0; mf < 4; ++mf)
#pragma unroll
        for (int reg = 0; reg < 4; ++reg)
            Lds[(mf * 16 + quad * 4 + reg) * 68 + pxl] = acc[mf][reg];
    __syncthreads();   // single barrier; LDS read-only hereafter

    // ---- coalesced copy-out: 64 oc-rows x 64 px (16 float4 per row) ----
    const int pixb = blockIdx.x * 64 & (HW_ - 1);   // block-base pixel
#pragma unroll
    for (int it = 0; it < 4; ++it) {
        const int j4 = it * 256 + tid;
        const int r  = j4 >> 4;                     // oc 0..63
        const int c4 = j4 & 15;                     // float4 col
        float4 v;
        v.x = Lds[r * 68 + c4 * 4 + 0];
        v.y = Lds[r * 68 + c4 * 4 + 1];
        v.z = Lds[r * 68 + c4 * 4 + 2];
        v.w = Lds[r * 68 + c4 * 4 + 3];
        *(float4*)&out[((size_t)(b * C_ + r)) * HW_ + pixb + c4 * 4] = v;
    }
}

// ---------------------------------------------------------------------------
extern "C" void kernel_launch(void* const* d_in, const int* in_sizes, int n_in,
                              void* d_out, int out_size, void* d_ws, size_t ws_size,
                              hipStream_t stream)
{
    const float* x    = (const float*)d_in[0];
    const float* ef   = (const float*)d_in[1];
    const float* flow = (const float*)d_in[2];
    const float* w1   = (const float*)d_in[3];
    const float* b1   = (const float*)d_in[4];
    const float* w2   = (const float*)d_in[5];
    const float* b2   = (const float*)d_in[6];
    const float* w3   = (const float*)d_in[7];
    const float* b3   = (const float*)d_in[8];
    const float* wk   = (const float*)d_in[9];
    float* out = (float*)d_out;

    // Workspace (half slots):
    //   omh 14,155,776 | valh 18,874,368 | ef_p 4*B*HWP*32 = 4,326,400
    //   xn 2,097,152 | h1p 2*B*HWP*32 = 2,163,200 | h2p 2,163,200
    //   w1A 73,728 | w2A 36,864 | w3A 248,832 | wkA 36,864
    _Float16* omh  = (_Float16*)d_ws;
    _Float16* valh = omh + (size_t)B_ * OFFC_ * HW_;
    _Float16* ef_p = valh + (size_t)18 * B_ * HW_ * 32;
    _Float16* xn   = ef_p + (size_t)4 * B_ * HWP_ * 32;
    _Float16* h1p  = xn + (size_t)B_ * HW_ * 64;
    _Float16* h2p  = h1p + (size_t)2 * B_ * HWP_ * 32;
    _Float16* w1A  = h2p + (size_t)2 * B_ * HWP_ * 32;
    _Float16* w2A  = w1A + 64 * 128 * 9;
    _Float16* w3A  = w2A + 64 * 64 * 9;
    _Float16* wkA  = w3A + OFFC_ * 64 * 9;

    // Zero the padded buffers (borders must be 0; interiors overwritten).
    hipMemsetAsync(ef_p, 0, (size_t)4 * B_ * HWP_ * 32 * 2, stream);
    hipMemsetAsync(h1p, 0, (size_t)2 * B_ * HWP_ * 32 * 2, stream);
    hipMemsetAsync(h2p, 0, (size_t)2 * B_ * HWP_ * 32 * 2, stream);

    prep_wA_k<64, 128><<<dim3((64 * 128 * 9 + 255) / 256), 256, 0, stream>>>(w1, w1A);
    prep_wA_k<64, 64><<<dim3((64 * 64 * 9 + 255) / 256), 256, 0, stream>>>(w2, w2A);
    prep_wA_k<OFFC_, 64><<<dim3((OFFC_ * 64 * 9 + 255) / 256), 256, 0, stream>>>(w3, w3A);
    prep_wkA_k<<<dim3((18 * 64 * 32 + 255) / 256), 256, 0, stream>>>(wk, wkA);
    nchw2slabpad_f16_k<128><<<dim3(HW_ / 256, B_), 256, 0, stream>>>(ef, ef_p);
    nchw2nhwc_f16_k<64><<<dim3(HW_ / 256, B_), 256, 0, stream>>>(x, xn);

    conv12_mfma_k<128><<<dim3(B_ * H_ * 2, 4), 256, 0, stream>>>(ef_p, w1A, b1, h1p);
    conv12_mfma_k<64><<<dim3(B_ * H_ * 2, 4), 256, 0, stream>>>(h1p, w2A, b2, h2p);
    conv3_mfma_k<<<dim3(B_ * H_, 9), 256, 0, stream>>>(h2p, w3A, b3, flow, omh);

    gather_k<<<dim3(HW_ / 16, B_ * KK_), 256, 0, stream>>>(xn, omh, valh);
    einsum_mfma_k<<<dim3(B_ * HW_ / 64), 256, 0, stream>>>(valh, wkA, out);
}